// Round 12
// baseline (2480.460 us; speedup 1.0000x reference)
//
#include <hip/hip_runtime.h>
#include <stdint.h>

#define T_ 128
#define B_ 256
#define D_ 512
#define H_ 768
#define NG 3072   // 4*H
#define OUT_ 60

using bf16x8 = __attribute__((ext_vector_type(8))) __bf16;
using f32x4  = __attribute__((ext_vector_type(4))) float;
using u32x4  = __attribute__((ext_vector_type(4))) unsigned int;

// ---------------- ws layout (bytes) ----------------
#define OFF_XB   ((size_t)0)                        // x bf16 linear [T*B][D]
#define OFF_WI   (OFF_XB + (size_t)T_*B_*D_*2)      // W_ih bf16 linear [NG][D]
#define OFF_WHPK (OFF_WI + (size_t)NG*D_*2)         // W_hh frag-packed per strip
#define OFF_H    (OFF_WHPK + (size_t)NG*H_*2)       // h dbuf [2][8g][32][768] bf16
#define OFF_HT   (OFF_H + (size_t)2*B_*H_*2)        // final h f32
#define OFF_BAR  (OFF_HT + (size_t)B_*H_*4)         // flags/probe, 64KB
#define OFF_XP   (OFF_BAR + 65536)                  // xp row-major [T*B][NG] bf16, 201MB
#define OFF_END  (OFF_XP + (size_t)T_*B_*NG*2)
// bar[] u32 map: flagA [(g*32+s)*16] in [0,2048) — ATOMIC-L2 ONLY;
// flagB [2048+(g*32+s)*16] — sc1 ONLY; xcc publish [4096+blk]; init ctr [5120]

__device__ __forceinline__ unsigned short f2bf(float f) {
  union { float f; unsigned u; } v; v.f = f;
  unsigned r = (v.u + 0x7fffu + ((v.u >> 16) & 1u)) >> 16;  // RNE
  return (unsigned short)r;
}
__device__ __forceinline__ float sigf(float x) {
  return __builtin_amdgcn_rcpf(1.0f + __expf(-x));
}
__device__ __forceinline__ float tanhf_(float x) {
  return 2.0f * __builtin_amdgcn_rcpf(1.0f + __expf(-2.0f * x)) - 1.0f;
}
__device__ __forceinline__ void gload16(const void* g, void* l) {
  __builtin_amdgcn_global_load_lds(
      (const __attribute__((address_space(1))) unsigned int*)g,
      (__attribute__((address_space(3))) unsigned int*)l, 16, 0, 0);
}
template<int OFF, bool SC1>
__device__ __forceinline__ u32x4 ld16(const void* p) {
  u32x4 r;
  if constexpr (SC1)
    asm volatile("global_load_dwordx4 %0, %1, off offset:%c2 sc0 sc1"
                 : "=v"(r) : "v"(p), "i"(OFF) : "memory");
  else
    asm volatile("global_load_dwordx4 %0, %1, off offset:%c2 sc0"
                 : "=v"(r) : "v"(p), "i"(OFF) : "memory");
  return r;
}
__device__ __forceinline__ unsigned ld4coh(const unsigned* p) {  // L3 poll (+wait)
  unsigned r;
  asm volatile("global_load_dword %0, %1, off sc0 sc1\n\ts_waitcnt vmcnt(0)"
               : "=v"(r) : "v"(p) : "memory");
  return r;
}
template<bool SC1>
__device__ __forceinline__ void st16g(void* p, u32x4 v) {
  if constexpr (SC1)
    asm volatile("global_store_dwordx4 %0, %1, off sc0 sc1" :: "v"(p), "v"(v) : "memory");
  else
    asm volatile("global_store_dwordx4 %0, %1, off sc0" :: "v"(p), "v"(v) : "memory");
}
__device__ __forceinline__ void st4coh(unsigned* p, unsigned v) {
  asm volatile("global_store_dword %0, %1, off sc0 sc1" :: "v"(p), "v"(v) : "memory");
}
// intra-XCD flag primitives: atomics execute AT the local L2, bypass L1 entirely.
__device__ __forceinline__ void atom_swap_l2(unsigned* p, unsigned v) {  // post
  asm volatile("global_atomic_swap %0, %1, off" :: "v"(p), "v"(v) : "memory");
}
__device__ __forceinline__ unsigned atom_rd_l2(unsigned* p) {  // add 0, return old (+wait)
  unsigned r; unsigned z = 0;
  asm volatile("global_atomic_add %0, %1, %2, off sc0\n\ts_waitcnt vmcnt(0)"
               : "=v"(r) : "v"(p), "v"(z) : "memory");
  return r;
}

// ---------------- phase A: convert + pack + init ----------------
__global__ void prep_kernel(const float* __restrict__ x,
                            const float* __restrict__ wihf,
                            const float* __restrict__ whhf,
                            uint8_t* __restrict__ ws) {
  ushort* xb = (ushort*)(ws + OFF_XB);
  ushort* wi = (ushort*)(ws + OFF_WI);
  ushort* whpk = (ushort*)(ws + OFF_WHPK);
  unsigned* bar = (unsigned*)(ws + OFF_BAR);
  const size_t tid = (size_t)blockIdx.x * blockDim.x + threadIdx.x;
  const size_t nth = (size_t)gridDim.x * blockDim.x;

  for (size_t i = tid; i < (size_t)T_*B_*D_/4; i += nth) {
    float4 v = ((const float4*)x)[i];
    ushort4 o; o.x=f2bf(v.x); o.y=f2bf(v.y); o.z=f2bf(v.z); o.w=f2bf(v.w);
    ((ushort4*)xb)[i] = o;
  }
  for (size_t i = tid; i < (size_t)NG*D_/4; i += nth) {
    float4 v = ((const float4*)wihf)[i];
    ushort4 o; o.x=f2bf(v.x); o.y=f2bf(v.y); o.z=f2bf(v.z); o.w=f2bf(v.w);
    ((ushort4*)wi)[i] = o;
  }
  // W_hh -> frag-packed per strip: chunk ((s*24+kf)*6+nt)*64+L  (verified R5)
  for (size_t c = tid; c < (size_t)294912; c += nth) {
    const unsigned L = (unsigned)c & 63u;
    const unsigned r1 = (unsigned)(c >> 6);
    const unsigned nt = r1 % 6u, r2 = r1 / 6u;
    const unsigned kf = r2 % 24u, s = r2 / 24u;
    const unsigned i = nt*16u + (L & 15u);
    const unsigned G = (i & 3u)*768u + s*24u + (i >> 2);
    const unsigned k0 = kf*32u + (L >> 4)*8u;
    const float4 v0 = *(const float4*)(whhf + (size_t)G*768u + k0);
    const float4 v1 = *(const float4*)(whhf + (size_t)G*768u + k0 + 4);
    ushort4 o0, o1;
    o0.x=f2bf(v0.x); o0.y=f2bf(v0.y); o0.z=f2bf(v0.z); o0.w=f2bf(v0.w);
    o1.x=f2bf(v1.x); o1.y=f2bf(v1.y); o1.z=f2bf(v1.z); o1.w=f2bf(v1.w);
    *(ushort4*)(whpk + c*8)     = o0;
    *(ushort4*)(whpk + c*8 + 4) = o1;
  }
  // zero flag/probe region THROUGH the coherence point (replay-safe)
  for (size_t i = tid; i < 16384; i += nth) st4coh(&bar[i], 0u);
}

// ---------------- phase B: xp = x @ W_ih^T (128x128 tile, BK=64; verified R2) ----------------
__global__ __launch_bounds__(256) void xproj_kernel(uint8_t* __restrict__ ws) {
  const ushort* __restrict__ xb = (const ushort*)(ws + OFF_XB);
  const ushort* __restrict__ wi = (const ushort*)(ws + OFF_WI);
  ushort* __restrict__ xp = (ushort*)(ws + OFF_XP);

  __shared__ ushort smA[128*64];
  __shared__ ushort smB[128*64];

  const int tid = threadIdx.x;
  const int lane = tid & 63;
  const int w = tid >> 6;
  const int bn = blockIdx.x % 24;
  const int bm = blockIdx.x / 24;
  const int m0 = bm * 128, n0 = bn * 128;
  const int mi = (w >> 1) * 64, ni = (w & 1) * 64;

  f32x4 acc[4][4] = {};

  for (int k0 = 0; k0 < D_; k0 += 64) {
    __syncthreads();
    #pragma unroll
    for (int i = 0; i < 4; ++i) {
      const int ig = w*4 + i;
      const int o  = ig*1024 + lane*16;
      const int row = o >> 7;
      const int colB = o & 127;
      const int scol = colB ^ ((row & 7) << 4);
      gload16((const uint8_t*)xb + ((size_t)(m0+row)*D_ + k0)*2 + scol,
              (uint8_t*)smA + ig*1024);
      gload16((const uint8_t*)wi + ((size_t)(n0+row)*D_ + k0)*2 + scol,
              (uint8_t*)smB + ig*1024);
    }
    __syncthreads();
    #pragma unroll
    for (int kk = 0; kk < 2; ++kk) {
      const int colB = kk*64 + (lane >> 4)*16;
      bf16x8 a[4], b[4];
      #pragma unroll
      for (int mt = 0; mt < 4; ++mt) {
        const int row = mi + mt*16 + (lane & 15);
        a[mt] = *(const bf16x8*)((const uint8_t*)smA + row*128 + (colB ^ ((row & 7) << 4)));
      }
      #pragma unroll
      for (int nt = 0; nt < 4; ++nt) {
        const int row = ni + nt*16 + (lane & 15);
        b[nt] = *(const bf16x8*)((const uint8_t*)smB + row*128 + (colB ^ ((row & 7) << 4)));
      }
      #pragma unroll
      for (int mt = 0; mt < 4; ++mt)
        #pragma unroll
        for (int nt = 0; nt < 4; ++nt)
          acc[mt][nt] = __builtin_amdgcn_mfma_f32_16x16x32_bf16(a[mt], b[nt], acc[mt][nt], 0, 0, 0);
    }
  }
  #pragma unroll
  for (int mt = 0; mt < 4; ++mt)
    #pragma unroll
    for (int nt = 0; nt < 4; ++nt) {
      const int r0 = m0 + mi + mt*16 + (lane >> 4)*4;
      const int c  = n0 + ni + nt*16 + (lane & 15);
      #pragma unroll
      for (int r = 0; r < 4; ++r)
        xp[(size_t)(r0 + r)*NG + c] = f2bf(acc[mt][nt][r]);
    }
}

// ---------------- phase C: persistent recurrence, L2-atomic flags ----------------
template<bool SC1>
__device__ __forceinline__ void run_loop(uint8_t* ws, const ushort* whh_lds, float* gbuf,
                                         ushort* hstage,
                                         const float* bih, const float* bhh,
                                         int tid, int g, int s) {
  const int lane = tid & 63, w = tid >> 6, wq = w & 1, wm = w >> 1;
  const int l15 = lane & 15, hi = lane >> 4;
  ushort* hb = (ushort*)(ws + OFF_H);
  const ushort* xp = (const ushort*)(ws + OFF_XP);
  float* hT = (float*)(ws + OFF_HT);
  unsigned* bar = (unsigned*)(ws + OFF_BAR);
  float* gw = gbuf + w*816;

  float bias[3][4];
  #pragma unroll
  for (int j = 0; j < 3; ++j) {
    const int col = s*24 + wq*12 + hi + 4*j;
    #pragma unroll
    for (int q = 0; q < 4; ++q) bias[j][q] = bih[q*H_ + col] + bhh[q*H_ + col];
  }
  const int pl = (lane < 32) ? lane : 31;
  unsigned* fpA = bar + (size_t)(g*32 + pl) * 16;
  const unsigned* fpB = bar + 2048 + (size_t)(g*32 + pl) * 16;

  // per-thread xp source: row = g*32+wm*16+l15, cols q*768 + s*24+wq*12+hi (+4j)
  const ushort* xpb = xp + (size_t)(g*32 + wm*16 + l15)*NG + s*24 + wq*12 + hi;
  ushort xq[12];   // [q][j], plain loads (compiler-managed waitcnt)
  {
    const ushort* p = xpb;
    #pragma unroll
    for (int q = 0; q < 4; ++q)
      #pragma unroll
      for (int j = 0; j < 3; ++j)
        xq[q*3+j] = p[q*768 + 4*j];
  }

  float cc[3] = {0.f, 0.f, 0.f};

  #pragma unroll 1
  for (int t = 0; t < T_; ++t) {
    f32x4 acc[3] = {};
    if (t > 0) {
      if (w == 0) {   // wait: all 32 strips posted h(t)
        int spins = 0;
        while (1) {
          unsigned v = SC1 ? ld4coh(fpB) : atom_rd_l2(fpA);
          if (__all((int)(v >= (unsigned)t))) break;
          if (!SC1 && ((++spins) & 1023) == 0) {
            const unsigned vb = ld4coh(fpB);   // separate-line liveness escape
            if (__all((int)(vb >= (unsigned)t))) break;
          }
          __builtin_amdgcn_s_sleep(1);
        }
      }
      __syncthreads();
      // h A-frags: 24 x 16B loads (L2-local in intra-XCD mode)
      const ushort* hr = hb + ((size_t)(t & 1)*8 + g)*((size_t)32*H_)
                         + (size_t)(wm*16 + l15)*H_ + hi*8;
      u32x4 ah[24];
      #define LH(i) ah[i] = ld16<(i)*64, SC1>(hr)
      LH(0); LH(1); LH(2); LH(3); LH(4); LH(5); LH(6); LH(7);
      LH(8); LH(9); LH(10); LH(11); LH(12); LH(13); LH(14); LH(15);
      LH(16); LH(17); LH(18); LH(19); LH(20); LH(21); LH(22); LH(23);
      #undef LH
      asm volatile("s_waitcnt vmcnt(0)" ::: "memory");
      __builtin_amdgcn_sched_barrier(0);
      #pragma unroll
      for (int kf = 0; kf < 24; ++kf) {
        const bf16x8 a = *(const bf16x8*)&ah[kf];
        #pragma unroll
        for (int n = 0; n < 3; ++n) {
          const bf16x8 b = *(const bf16x8*)(whh_lds + (size_t)((kf*6 + wq*3 + n)*64 + lane)*8);
          acc[n] = __builtin_amdgcn_mfma_f32_16x16x32_bf16(a, b, acc[n], 0, 0, 0);
        }
      }
    }
    // gate xpose (wave-local LDS region, no barrier) + activations (+ xp + bias)
    #pragma unroll
    for (int n = 0; n < 3; ++n)
      #pragma unroll
      for (int r = 0; r < 4; ++r)
        gw[(n*16 + l15)*17 + hi*4 + r] = acc[n][r];
    float hv[3];
    #pragma unroll
    for (int j = 0; j < 3; ++j) {
      const int cl = hi + 4*j;
      float gq[4];
      #pragma unroll
      for (int q = 0; q < 4; ++q) {
        union { unsigned u; float f; } xv; xv.u = ((unsigned)xq[q*3 + j]) << 16;
        gq[q] = gw[(cl*4+q)*17 + l15] + xv.f + bias[j][q];
      }
      const float iv = sigf(gq[0]);
      const float fv = sigf(gq[1]);
      const float gv = tanhf_(gq[2]);
      const float ov = sigf(gq[3]);
      const float cn = fv*cc[j] + iv*gv;
      cc[j] = cn;
      hv[j] = ov * tanhf_(cn);
    }
    const int rowl = wm*16 + l15;
    if (t == T_-1) {
      #pragma unroll
      for (int j = 0; j < 3; ++j) {
        const int col = s*24 + wq*12 + hi + 4*j;
        hT[(size_t)(g*32 + rowl)*H_ + col] = hv[j];
      }
      break;
    }
    // stage h in LDS, then 96 coalesced 16B stores (validated R8)
    #pragma unroll
    for (int j = 0; j < 3; ++j)
      hstage[rowl*24 + wq*12 + hi + 4*j] = f2bf(hv[j]);
    __syncthreads();
    ushort* hn = hb + ((size_t)((t+1) & 1)*8 + g)*((size_t)32*H_);
    if (tid < 96) {
      const int row = tid / 3, part = tid % 3;
      const u32x4 v = *(const u32x4*)((const uint8_t*)hstage + row*48 + part*16);
      st16g<SC1>(hn + (size_t)row*H_ + s*24 + part*8, v);
      asm volatile("s_waitcnt vmcnt(0)" ::: "memory");   // own stores landed
    }
    __syncthreads();                                      // all 96 stores acked
    if (tid == 0) {
      if (!SC1) atom_swap_l2(bar + (size_t)(g*32 + s)*16, (unsigned)(t + 1)); // L2 atomic
      st4coh(bar + 2048 + (size_t)(g*32 + s)*16, (unsigned)(t + 1));          // sc1 line
    }
    {  // prefetch xp(t+1) in the post-flag slack (plain loads)
      const ushort* p = xpb + (size_t)(t + 1)*B_*NG;
      #pragma unroll
      for (int q = 0; q < 4; ++q)
        #pragma unroll
        for (int j = 0; j < 3; ++j)
          xq[q*3+j] = p[q*768 + 4*j];
    }
  }
}

__global__ __launch_bounds__(256, 1) void lstm_kernel(uint8_t* __restrict__ ws,
                                                      const float* __restrict__ bih,
                                                      const float* __restrict__ bhh) {
  __shared__ ushort whh_lds[73728];   // 144 KB: [kf 24][nt 6][64] 16B frag chunks
  __shared__ float gbuf[3264];        // 12.75 KB
  __shared__ ushort hstage[768];      // 1.5 KB: [row 32][col 24]
  const int tid = threadIdx.x, lane = tid & 63, w = tid >> 6;
  const int g = blockIdx.x & 7, s = blockIdx.x >> 3;
  unsigned* bar = (unsigned*)(ws + OFF_BAR);

  const uint8_t* wsrc = ws + OFF_WHPK + (size_t)s*9216*16;
  #pragma unroll
  for (int i = 0; i < 36; ++i) {
    const int cb = (w*36 + i)*64;
    gload16(wsrc + (size_t)(cb + lane)*16, (uint8_t*)whh_lds + (size_t)cb*16);
  }

  // reset my flagA AT MY L2 (kills cross-replay staleness), publish XCC, init barrier
  const unsigned xcd = __builtin_amdgcn_s_getreg((3 << 11) | 20) & 7u;  // HW_REG_XCC_ID
  if (tid == 0) {
    atom_swap_l2(bar + (size_t)(g*32 + s)*16, 0u);
    st4coh(bar + 4096 + blockIdx.x, xcd);
    asm volatile("s_waitcnt vmcnt(0)" ::: "memory");
    __hip_atomic_fetch_add(bar + 5120, 1u, __ATOMIC_RELAXED, __HIP_MEMORY_SCOPE_SYSTEM);
    while (__hip_atomic_load(bar + 5120, __ATOMIC_RELAXED, __HIP_MEMORY_SCOPE_SYSTEM) < 256u)
      __builtin_amdgcn_s_sleep(2);
  }
  __syncthreads();
  const int pl = (lane < 32) ? lane : 31;
  const unsigned oxcc = ld4coh(bar + 4096 + g + 8*pl);   // peers of my group
  const bool local = __all((int)(oxcc == xcd));

  asm volatile("s_waitcnt vmcnt(0) lgkmcnt(0)" ::: "memory");
  __syncthreads();                                 // whh_lds fully staged

  if (local) run_loop<false>(ws, whh_lds, gbuf, hstage, bih, bhh, tid, g, s);
  else       run_loop<true >(ws, whh_lds, gbuf, hstage, bih, bhh, tid, g, s);
}

// ---------------- phase D: out = h_T @ W_fc^T + b_fc ----------------
__global__ __launch_bounds__(64) void fc_kernel(const uint8_t* __restrict__ ws,
                                                const float* __restrict__ wfc,
                                                const float* __restrict__ bfc,
                                                float* __restrict__ out) {
  const float* hT = (const float*)(ws + OFF_HT);
  const int b = blockIdx.x;
  const int lane = threadIdx.x;
  const float* hr = hT + (size_t)b*H_;
  float hv[12];
  #pragma unroll
  for (int i = 0; i < 12; ++i) hv[i] = hr[lane + i*64];
  for (int o = 0; o < OUT_; ++o) {
    const float* wr = wfc + (size_t)o*H_;
    float sum = 0.f;
    #pragma unroll
    for (int i = 0; i < 12; ++i) sum += hv[i] * wr[lane + i*64];
    #pragma unroll
    for (int off = 32; off; off >>= 1) sum += __shfl_xor(sum, off);
    if (lane == 0) out[(size_t)b*OUT_ + o] = sum + bfc[o];
  }
}

extern "C" void kernel_launch(void* const* d_in, const int* in_sizes, int n_in,
                              void* d_out, int out_size, void* d_ws, size_t ws_size,
                              hipStream_t stream) {
  const float* x   = (const float*)d_in[0];
  const float* wih = (const float*)d_in[1];
  const float* whh = (const float*)d_in[2];
  const float* bih = (const float*)d_in[3];
  const float* bhh = (const float*)d_in[4];
  const float* wfc = (const float*)d_in[5];
  const float* bfc = (const float*)d_in[6];
  uint8_t* ws = (uint8_t*)d_ws;
  float* out = (float*)d_out;

  prep_kernel<<<dim3(2048), dim3(256), 0, stream>>>(x, wih, whh, ws);
  xproj_kernel<<<dim3(256*24), dim3(256), 0, stream>>>(ws);
  lstm_kernel<<<dim3(256), dim3(256), 0, stream>>>(ws, bih, bhh);
  fc_kernel<<<dim3(256), dim3(64), 0, stream>>>(ws, wfc, bfc, out);
}

// Round 13
// 1133.115 us; speedup vs baseline: 2.1891x; 2.1891x over previous
//
#include <hip/hip_runtime.h>
#include <stdint.h>

#define T_ 128
#define B_ 256
#define D_ 512
#define H_ 768
#define NG 3072   // 4*H
#define OUT_ 60

using bf16x8 = __attribute__((ext_vector_type(8))) __bf16;
using f32x4  = __attribute__((ext_vector_type(4))) float;
using u32x4  = __attribute__((ext_vector_type(4))) unsigned int;

// ---------------- ws layout (bytes) ----------------
#define OFF_XB   ((size_t)0)                        // x bf16 linear [T*B][D]
#define OFF_WI   (OFF_XB + (size_t)T_*B_*D_*2)      // W_ih bf16 linear [NG][D]
#define OFF_WHPK (OFF_WI + (size_t)NG*D_*2)         // W_hh frag-packed per strip
#define OFF_H    (OFF_WHPK + (size_t)NG*H_*2)       // h dbuf [2][8g][32][768] bf16
#define OFF_HT   (OFF_H + (size_t)2*B_*H_*2)        // final h f32
#define OFF_BAR  (OFF_HT + (size_t)B_*H_*4)         // flags/probe, 64KB
#define OFF_XP   (OFF_BAR + 65536)                  // xp row-major [T*B][NG] bf16, 201MB
#define OFF_END  (OFF_XP + (size_t)T_*B_*NG*2)
// bar[] u32 map: flags [(g*32+s)*16] — sc1 ONLY (R7-proven semantics);
// xcc publish [4096+blk]; init ctr [5120]

__device__ __forceinline__ unsigned short f2bf(float f) {
  union { float f; unsigned u; } v; v.f = f;
  unsigned r = (v.u + 0x7fffu + ((v.u >> 16) & 1u)) >> 16;  // RNE
  return (unsigned short)r;
}
__device__ __forceinline__ float sigf(float x) {
  return __builtin_amdgcn_rcpf(1.0f + __expf(-x));
}
__device__ __forceinline__ float tanhf_(float x) {
  return 2.0f * __builtin_amdgcn_rcpf(1.0f + __expf(-2.0f * x)) - 1.0f;
}
__device__ __forceinline__ void gload16(const void* g, void* l) {
  __builtin_amdgcn_global_load_lds(
      (const __attribute__((address_space(1))) unsigned int*)g,
      (__attribute__((address_space(3))) unsigned int*)l, 16, 0, 0);
}
template<int OFF, bool SC1>
__device__ __forceinline__ u32x4 ld16(const void* p) {
  u32x4 r;
  if constexpr (SC1)
    asm volatile("global_load_dwordx4 %0, %1, off offset:%c2 sc0 sc1"
                 : "=v"(r) : "v"(p), "i"(OFF) : "memory");
  else
    asm volatile("global_load_dwordx4 %0, %1, off offset:%c2 sc0"
                 : "=v"(r) : "v"(p), "i"(OFF) : "memory");
  return r;
}
__device__ __forceinline__ unsigned ld4coh(const unsigned* p) {  // sc1 poll (+wait)
  unsigned r;
  asm volatile("global_load_dword %0, %1, off sc0 sc1\n\ts_waitcnt vmcnt(0)"
               : "=v"(r) : "v"(p) : "memory");
  return r;
}
template<bool SC1>
__device__ __forceinline__ void st16g(void* p, u32x4 v) {
  if constexpr (SC1)
    asm volatile("global_store_dwordx4 %0, %1, off sc0 sc1" :: "v"(p), "v"(v) : "memory");
  else
    asm volatile("global_store_dwordx4 %0, %1, off sc0" :: "v"(p), "v"(v) : "memory");
}
__device__ __forceinline__ void st4coh(unsigned* p, unsigned v) {
  asm volatile("global_store_dword %0, %1, off sc0 sc1" :: "v"(p), "v"(v) : "memory");
}

// ---------------- phase A: convert + pack + init ----------------
__global__ void prep_kernel(const float* __restrict__ x,
                            const float* __restrict__ wihf,
                            const float* __restrict__ whhf,
                            uint8_t* __restrict__ ws) {
  ushort* xb = (ushort*)(ws + OFF_XB);
  ushort* wi = (ushort*)(ws + OFF_WI);
  ushort* whpk = (ushort*)(ws + OFF_WHPK);
  unsigned* bar = (unsigned*)(ws + OFF_BAR);
  const size_t tid = (size_t)blockIdx.x * blockDim.x + threadIdx.x;
  const size_t nth = (size_t)gridDim.x * blockDim.x;

  for (size_t i = tid; i < (size_t)T_*B_*D_/4; i += nth) {
    float4 v = ((const float4*)x)[i];
    ushort4 o; o.x=f2bf(v.x); o.y=f2bf(v.y); o.z=f2bf(v.z); o.w=f2bf(v.w);
    ((ushort4*)xb)[i] = o;
  }
  for (size_t i = tid; i < (size_t)NG*D_/4; i += nth) {
    float4 v = ((const float4*)wihf)[i];
    ushort4 o; o.x=f2bf(v.x); o.y=f2bf(v.y); o.z=f2bf(v.z); o.w=f2bf(v.w);
    ((ushort4*)wi)[i] = o;
  }
  // W_hh -> frag-packed per strip: chunk ((s*24+kf)*6+nt)*64+L  (verified R5)
  for (size_t c = tid; c < (size_t)294912; c += nth) {
    const unsigned L = (unsigned)c & 63u;
    const unsigned r1 = (unsigned)(c >> 6);
    const unsigned nt = r1 % 6u, r2 = r1 / 6u;
    const unsigned kf = r2 % 24u, s = r2 / 24u;
    const unsigned i = nt*16u + (L & 15u);
    const unsigned G = (i & 3u)*768u + s*24u + (i >> 2);
    const unsigned k0 = kf*32u + (L >> 4)*8u;
    const float4 v0 = *(const float4*)(whhf + (size_t)G*768u + k0);
    const float4 v1 = *(const float4*)(whhf + (size_t)G*768u + k0 + 4);
    ushort4 o0, o1;
    o0.x=f2bf(v0.x); o0.y=f2bf(v0.y); o0.z=f2bf(v0.z); o0.w=f2bf(v0.w);
    o1.x=f2bf(v1.x); o1.y=f2bf(v1.y); o1.z=f2bf(v1.z); o1.w=f2bf(v1.w);
    *(ushort4*)(whpk + c*8)     = o0;
    *(ushort4*)(whpk + c*8 + 4) = o1;
  }
  // zero flag/probe region THROUGH the coherence point (replay-safe)
  for (size_t i = tid; i < 16384; i += nth) st4coh(&bar[i], 0u);
}

// ---------------- phase B: xp = x @ W_ih^T (128x128 tile, BK=64; verified R2) ----------------
__global__ __launch_bounds__(256) void xproj_kernel(uint8_t* __restrict__ ws) {
  const ushort* __restrict__ xb = (const ushort*)(ws + OFF_XB);
  const ushort* __restrict__ wi = (const ushort*)(ws + OFF_WI);
  ushort* __restrict__ xp = (ushort*)(ws + OFF_XP);

  __shared__ ushort smA[128*64];
  __shared__ ushort smB[128*64];

  const int tid = threadIdx.x;
  const int lane = tid & 63;
  const int w = tid >> 6;
  const int bn = blockIdx.x % 24;
  const int bm = blockIdx.x / 24;
  const int m0 = bm * 128, n0 = bn * 128;
  const int mi = (w >> 1) * 64, ni = (w & 1) * 64;

  f32x4 acc[4][4] = {};

  for (int k0 = 0; k0 < D_; k0 += 64) {
    __syncthreads();
    #pragma unroll
    for (int i = 0; i < 4; ++i) {
      const int ig = w*4 + i;
      const int o  = ig*1024 + lane*16;
      const int row = o >> 7;
      const int colB = o & 127;
      const int scol = colB ^ ((row & 7) << 4);
      gload16((const uint8_t*)xb + ((size_t)(m0+row)*D_ + k0)*2 + scol,
              (uint8_t*)smA + ig*1024);
      gload16((const uint8_t*)wi + ((size_t)(n0+row)*D_ + k0)*2 + scol,
              (uint8_t*)smB + ig*1024);
    }
    __syncthreads();
    #pragma unroll
    for (int kk = 0; kk < 2; ++kk) {
      const int colB = kk*64 + (lane >> 4)*16;
      bf16x8 a[4], b[4];
      #pragma unroll
      for (int mt = 0; mt < 4; ++mt) {
        const int row = mi + mt*16 + (lane & 15);
        a[mt] = *(const bf16x8*)((const uint8_t*)smA + row*128 + (colB ^ ((row & 7) << 4)));
      }
      #pragma unroll
      for (int nt = 0; nt < 4; ++nt) {
        const int row = ni + nt*16 + (lane & 15);
        b[nt] = *(const bf16x8*)((const uint8_t*)smB + row*128 + (colB ^ ((row & 7) << 4)));
      }
      #pragma unroll
      for (int mt = 0; mt < 4; ++mt)
        #pragma unroll
        for (int nt = 0; nt < 4; ++nt)
          acc[mt][nt] = __builtin_amdgcn_mfma_f32_16x16x32_bf16(a[mt], b[nt], acc[mt][nt], 0, 0, 0);
    }
  }
  #pragma unroll
  for (int mt = 0; mt < 4; ++mt)
    #pragma unroll
    for (int nt = 0; nt < 4; ++nt) {
      const int r0 = m0 + mi + mt*16 + (lane >> 4)*4;
      const int c  = n0 + ni + nt*16 + (lane & 15);
      #pragma unroll
      for (int r = 0; r < 4; ++r)
        xp[(size_t)(r0 + r)*NG + c] = f2bf(acc[mt][nt][r]);
    }
}

// ---------------- phase C: persistent recurrence, chunked arrival-ordered ----------------
// 256 WGs, 1/CU. 8 groups x 32 strips (group g == XCD g by round-robin).
// Flags: sc1 post + sc1 poll (R7-proven). Per step, each wave polls 8 chunks of
// 4 strips and consumes 3 k-frags per chunk as they arrive.
template<bool SC1>
__device__ __forceinline__ void run_loop(uint8_t* ws, const ushort* whh_lds, float* gbuf,
                                         ushort* hstage,
                                         const float* bih, const float* bhh,
                                         int tid, int g, int s) {
  const int lane = tid & 63, w = tid >> 6, wq = w & 1, wm = w >> 1;
  const int l15 = lane & 15, hi = lane >> 4;
  ushort* hb = (ushort*)(ws + OFF_H);
  const ushort* xp = (const ushort*)(ws + OFF_XP);
  float* hT = (float*)(ws + OFF_HT);
  unsigned* bar = (unsigned*)(ws + OFF_BAR);
  float* gw = gbuf + w*816;

  float bias[3][4];
  #pragma unroll
  for (int j = 0; j < 3; ++j) {
    const int col = s*24 + wq*12 + hi + 4*j;
    #pragma unroll
    for (int q = 0; q < 4; ++q) bias[j][q] = bih[q*H_ + col] + bhh[q*H_ + col];
  }

  // per-thread xp source: row = g*32+wm*16+l15, cols q*768 + s*24+wq*12+hi (+4j)
  const ushort* xpb = xp + (size_t)(g*32 + wm*16 + l15)*NG + s*24 + wq*12 + hi;
  ushort xq[12];   // [q][j], plain loads (compiler-managed waitcnt)
  {
    const ushort* p = xpb;
    #pragma unroll
    for (int q = 0; q < 4; ++q)
      #pragma unroll
      for (int j = 0; j < 3; ++j)
        xq[q*3+j] = p[q*768 + 4*j];
  }

  float cc[3] = {0.f, 0.f, 0.f};

  #pragma unroll 1
  for (int t = 0; t < T_; ++t) {
    f32x4 acc[3] = {};
    if (t > 0) {
      // base of my A-frag row in h(t)
      const uint8_t* hr = (const uint8_t*)(hb + ((size_t)(t & 1)*8 + g)*((size_t)32*H_)
                          + (size_t)(wm*16 + l15)*H_ + hi*8);
      // 8 chunks of 4 strips (96 cols = 3 k-frags each); every wave polls itself
      #pragma unroll 1
      for (int ch = 0; ch < 8; ++ch) {
        const unsigned* fp = bar + (size_t)(g*32 + ch*4 + (lane & 3)) * 16;
        while (1) {
          const unsigned v = ld4coh(fp);
          if (__all((int)(v >= (unsigned)t))) break;
          __builtin_amdgcn_s_sleep(1);
        }
        u32x4 a0 = ld16<  0, SC1>(hr + ch*192);
        u32x4 a1 = ld16< 64, SC1>(hr + ch*192);
        u32x4 a2 = ld16<128, SC1>(hr + ch*192);
        asm volatile("s_waitcnt vmcnt(0)" ::: "memory");
        __builtin_amdgcn_sched_barrier(0);
        #pragma unroll
        for (int kk = 0; kk < 3; ++kk) {
          const int kf = ch*3 + kk;
          const bf16x8 a = (kk == 0) ? *(const bf16x8*)&a0
                         : (kk == 1) ? *(const bf16x8*)&a1 : *(const bf16x8*)&a2;
          #pragma unroll
          for (int n = 0; n < 3; ++n) {
            const bf16x8 b = *(const bf16x8*)(whh_lds + (size_t)((kf*6 + wq*3 + n)*64 + lane)*8);
            acc[n] = __builtin_amdgcn_mfma_f32_16x16x32_bf16(a, b, acc[n], 0, 0, 0);
          }
        }
      }
    }
    // gate xpose (wave-local LDS region, no barrier) + activations (+ xp + bias)
    #pragma unroll
    for (int n = 0; n < 3; ++n)
      #pragma unroll
      for (int r = 0; r < 4; ++r)
        gw[(n*16 + l15)*17 + hi*4 + r] = acc[n][r];
    float hv[3];
    #pragma unroll
    for (int j = 0; j < 3; ++j) {
      const int cl = hi + 4*j;
      float gq[4];
      #pragma unroll
      for (int q = 0; q < 4; ++q) {
        union { unsigned u; float f; } xv; xv.u = ((unsigned)xq[q*3 + j]) << 16;
        gq[q] = gw[(cl*4+q)*17 + l15] + xv.f + bias[j][q];
      }
      const float iv = sigf(gq[0]);
      const float fv = sigf(gq[1]);
      const float gv = tanhf_(gq[2]);
      const float ov = sigf(gq[3]);
      const float cn = fv*cc[j] + iv*gv;
      cc[j] = cn;
      hv[j] = ov * tanhf_(cn);
    }
    const int rowl = wm*16 + l15;
    if (t == T_-1) {
      #pragma unroll
      for (int j = 0; j < 3; ++j) {
        const int col = s*24 + wq*12 + hi + 4*j;
        hT[(size_t)(g*32 + rowl)*H_ + col] = hv[j];
      }
      break;
    }
    // stage h in LDS, then 96 coalesced 16B stores (R8-validated mapping)
    #pragma unroll
    for (int j = 0; j < 3; ++j)
      hstage[rowl*24 + wq*12 + hi + 4*j] = f2bf(hv[j]);
    __syncthreads();
    ushort* hn = hb + ((size_t)((t+1) & 1)*8 + g)*((size_t)32*H_);
    if (tid < 96) {
      const int row = tid / 3, part = tid % 3;
      const u32x4 v = *(const u32x4*)((const uint8_t*)hstage + row*48 + part*16);
      st16g<SC1>(hn + (size_t)row*H_ + s*24 + part*8, v);
    }
    asm volatile("s_waitcnt vmcnt(0)" ::: "memory");   // stores landed (L2 / coh pt)
    __syncthreads();                                    // all 96 stores acked
    if (tid == 0) st4coh(bar + (size_t)(g*32 + s)*16, (unsigned)(t + 1));
    {  // prefetch xp(t+1) in the post-flag slack (plain loads)
      const ushort* p = xpb + (size_t)(t + 1)*B_*NG;
      #pragma unroll
      for (int q = 0; q < 4; ++q)
        #pragma unroll
        for (int j = 0; j < 3; ++j)
          xq[q*3+j] = p[q*768 + 4*j];
    }
  }
}

__global__ __launch_bounds__(256, 1) void lstm_kernel(uint8_t* __restrict__ ws,
                                                      const float* __restrict__ bih,
                                                      const float* __restrict__ bhh) {
  __shared__ ushort whh_lds[73728];   // 144 KB: [kf 24][nt 6][64] 16B frag chunks
  __shared__ float gbuf[3264];        // 12.75 KB
  __shared__ ushort hstage[768];      // 1.5 KB: [row 32][col 24]
  const int tid = threadIdx.x, lane = tid & 63, w = tid >> 6;
  const int g = blockIdx.x & 7, s = blockIdx.x >> 3;
  unsigned* bar = (unsigned*)(ws + OFF_BAR);

  const uint8_t* wsrc = ws + OFF_WHPK + (size_t)s*9216*16;
  #pragma unroll
  for (int i = 0; i < 36; ++i) {
    const int cb = (w*36 + i)*64;
    gload16(wsrc + (size_t)(cb + lane)*16, (uint8_t*)whh_lds + (size_t)cb*16);
  }

  // publish XCC_ID (sc1); one-time global init barrier (system atomic)
  const unsigned xcd = __builtin_amdgcn_s_getreg((3 << 11) | 20) & 7u;  // HW_REG_XCC_ID
  if (tid == 0) {
    st4coh(bar + 4096 + blockIdx.x, xcd);
    asm volatile("s_waitcnt vmcnt(0)" ::: "memory");
    __hip_atomic_fetch_add(bar + 5120, 1u, __ATOMIC_RELAXED, __HIP_MEMORY_SCOPE_SYSTEM);
    while (__hip_atomic_load(bar + 5120, __ATOMIC_RELAXED, __HIP_MEMORY_SCOPE_SYSTEM) < 256u)
      __builtin_amdgcn_s_sleep(2);
  }
  __syncthreads();
  const int pl = (lane < 32) ? lane : 31;
  const unsigned oxcc = ld4coh(bar + 4096 + g + 8*pl);   // peers of my group
  const bool local = __all((int)(oxcc == xcd));

  asm volatile("s_waitcnt vmcnt(0) lgkmcnt(0)" ::: "memory");
  __syncthreads();                                 // whh_lds fully staged

  if (local) run_loop<false>(ws, whh_lds, gbuf, hstage, bih, bhh, tid, g, s);
  else       run_loop<true >(ws, whh_lds, gbuf, hstage, bih, bhh, tid, g, s);
}

// ---------------- phase D: out = h_T @ W_fc^T + b_fc ----------------
__global__ __launch_bounds__(64) void fc_kernel(const uint8_t* __restrict__ ws,
                                                const float* __restrict__ wfc,
                                                const float* __restrict__ bfc,
                                                float* __restrict__ out) {
  const float* hT = (const float*)(ws + OFF_HT);
  const int b = blockIdx.x;
  const int lane = threadIdx.x;
  const float* hr = hT + (size_t)b*H_;
  float hv[12];
  #pragma unroll
  for (int i = 0; i < 12; ++i) hv[i] = hr[lane + i*64];
  for (int o = 0; o < OUT_; ++o) {
    const float* wr = wfc + (size_t)o*H_;
    float sum = 0.f;
    #pragma unroll
    for (int i = 0; i < 12; ++i) sum += hv[i] * wr[lane + i*64];
    #pragma unroll
    for (int off = 32; off; off >>= 1) sum += __shfl_xor(sum, off);
    if (lane == 0) out[(size_t)b*OUT_ + o] = sum + bfc[o];
  }
}

extern "C" void kernel_launch(void* const* d_in, const int* in_sizes, int n_in,
                              void* d_out, int out_size, void* d_ws, size_t ws_size,
                              hipStream_t stream) {
  const float* x   = (const float*)d_in[0];
  const float* wih = (const float*)d_in[1];
  const float* whh = (const float*)d_in[2];
  const float* bih = (const float*)d_in[3];
  const float* bhh = (const float*)d_in[4];
  const float* wfc = (const float*)d_in[5];
  const float* bfc = (const float*)d_in[6];
  uint8_t* ws = (uint8_t*)d_ws;
  float* out = (float*)d_out;

  prep_kernel<<<dim3(2048), dim3(256), 0, stream>>>(x, wih, whh, ws);
  xproj_kernel<<<dim3(256*24), dim3(256), 0, stream>>>(ws);
  lstm_kernel<<<dim3(256), dim3(256), 0, stream>>>(ws, bih, bhh);
  fc_kernel<<<dim3(256), dim3(64), 0, stream>>>(ws, wfc, bfc, out);
}

// Round 14
// 1030.403 us; speedup vs baseline: 2.4073x; 1.0997x over previous
//
#include <hip/hip_runtime.h>
#include <stdint.h>

#define T_ 128
#define B_ 256
#define D_ 512
#define H_ 768
#define NG 3072   // 4*H
#define OUT_ 60

using bf16x8 = __attribute__((ext_vector_type(8))) __bf16;
using f32x4  = __attribute__((ext_vector_type(4))) float;
using u32x4  = __attribute__((ext_vector_type(4))) unsigned int;

// ---------------- ws layout (bytes) ----------------
#define OFF_XB   ((size_t)0)                        // x bf16 linear [T*B][D]
#define OFF_WI   (OFF_XB + (size_t)T_*B_*D_*2)      // W_ih bf16 linear [NG][D]
#define OFF_WHPK (OFF_WI + (size_t)NG*D_*2)         // W_hh frag-packed per strip
#define OFF_H    (OFF_WHPK + (size_t)NG*H_*2)       // h dbuf [2][8g][32][768] bf16
#define OFF_HT   (OFF_H + (size_t)2*B_*H_*2)        // final h f32
#define OFF_BAR  (OFF_HT + (size_t)B_*H_*4)         // flags/probe, 64KB
#define OFF_XP   (OFF_BAR + 65536)                  // xp row-major [T*B][NG] bf16, 201MB
#define OFF_END  (OFF_XP + (size_t)T_*B_*NG*2)
// bar[] u32 map: flagA [(g*32+s)*16] in [0,2048) — sc0-ONLY writes, polled with
// buffer_inv+sc0; flagB [2048+(g*32+s)*16] — sc1-ONLY (liveness + fallback);
// xcc publish [4096+blk]; init ctr [5120].  R8 lesson: never mix sc0/sc1 on one line.

__device__ __forceinline__ unsigned short f2bf(float f) {
  union { float f; unsigned u; } v; v.f = f;
  unsigned r = (v.u + 0x7fffu + ((v.u >> 16) & 1u)) >> 16;  // RNE
  return (unsigned short)r;
}
__device__ __forceinline__ float sigf(float x) {
  return __builtin_amdgcn_rcpf(1.0f + __expf(-x));
}
__device__ __forceinline__ float tanhf_(float x) {
  return 2.0f * __builtin_amdgcn_rcpf(1.0f + __expf(-2.0f * x)) - 1.0f;
}
__device__ __forceinline__ void gload16(const void* g, void* l) {
  __builtin_amdgcn_global_load_lds(
      (const __attribute__((address_space(1))) unsigned int*)g,
      (__attribute__((address_space(3))) unsigned int*)l, 16, 0, 0);
}
template<int OFF, bool SC1>
__device__ __forceinline__ u32x4 ld16(const void* p) {
  u32x4 r;
  if constexpr (SC1)
    asm volatile("global_load_dwordx4 %0, %1, off offset:%c2 sc0 sc1"
                 : "=v"(r) : "v"(p), "i"(OFF) : "memory");
  else
    asm volatile("global_load_dwordx4 %0, %1, off offset:%c2 sc0"
                 : "=v"(r) : "v"(p), "i"(OFF) : "memory");
  return r;
}
// sc0 poll load (+wait): L2-served AFTER an L1 invalidate
__device__ __forceinline__ unsigned ld4sc0(const unsigned* p) {
  unsigned r;
  asm volatile("global_load_dword %0, %1, off sc0\n\ts_waitcnt vmcnt(0)"
               : "=v"(r) : "v"(p) : "memory");
  return r;
}
__device__ __forceinline__ unsigned ld4coh(const unsigned* p) {  // sc1 poll (+wait)
  unsigned r;
  asm volatile("global_load_dword %0, %1, off sc0 sc1\n\ts_waitcnt vmcnt(0)"
               : "=v"(r) : "v"(p) : "memory");
  return r;
}
__device__ __forceinline__ void l1_inv() {   // CU-local vector-L1 invalidate
  asm volatile("buffer_inv" ::: "memory");
}
template<bool SC1>
__device__ __forceinline__ void st16g(void* p, u32x4 v) {
  if constexpr (SC1)
    asm volatile("global_store_dwordx4 %0, %1, off sc0 sc1" :: "v"(p), "v"(v) : "memory");
  else
    asm volatile("global_store_dwordx4 %0, %1, off sc0" :: "v"(p), "v"(v) : "memory");
}
__device__ __forceinline__ void st4sc0(unsigned* p, unsigned v) {
  asm volatile("global_store_dword %0, %1, off sc0" :: "v"(p), "v"(v) : "memory");
}
__device__ __forceinline__ void st4coh(unsigned* p, unsigned v) {
  asm volatile("global_store_dword %0, %1, off sc0 sc1" :: "v"(p), "v"(v) : "memory");
}

// ---------------- phase A: convert + pack + init ----------------
__global__ void prep_kernel(const float* __restrict__ x,
                            const float* __restrict__ wihf,
                            const float* __restrict__ whhf,
                            uint8_t* __restrict__ ws) {
  ushort* xb = (ushort*)(ws + OFF_XB);
  ushort* wi = (ushort*)(ws + OFF_WI);
  ushort* whpk = (ushort*)(ws + OFF_WHPK);
  unsigned* bar = (unsigned*)(ws + OFF_BAR);
  const size_t tid = (size_t)blockIdx.x * blockDim.x + threadIdx.x;
  const size_t nth = (size_t)gridDim.x * blockDim.x;

  for (size_t i = tid; i < (size_t)T_*B_*D_/4; i += nth) {
    float4 v = ((const float4*)x)[i];
    ushort4 o; o.x=f2bf(v.x); o.y=f2bf(v.y); o.z=f2bf(v.z); o.w=f2bf(v.w);
    ((ushort4*)xb)[i] = o;
  }
  for (size_t i = tid; i < (size_t)NG*D_/4; i += nth) {
    float4 v = ((const float4*)wihf)[i];
    ushort4 o; o.x=f2bf(v.x); o.y=f2bf(v.y); o.z=f2bf(v.z); o.w=f2bf(v.w);
    ((ushort4*)wi)[i] = o;
  }
  // W_hh -> frag-packed per strip: chunk ((s*24+kf)*6+nt)*64+L  (verified R5)
  for (size_t c = tid; c < (size_t)294912; c += nth) {
    const unsigned L = (unsigned)c & 63u;
    const unsigned r1 = (unsigned)(c >> 6);
    const unsigned nt = r1 % 6u, r2 = r1 / 6u;
    const unsigned kf = r2 % 24u, s = r2 / 24u;
    const unsigned i = nt*16u + (L & 15u);
    const unsigned G = (i & 3u)*768u + s*24u + (i >> 2);
    const unsigned k0 = kf*32u + (L >> 4)*8u;
    const float4 v0 = *(const float4*)(whhf + (size_t)G*768u + k0);
    const float4 v1 = *(const float4*)(whhf + (size_t)G*768u + k0 + 4);
    ushort4 o0, o1;
    o0.x=f2bf(v0.x); o0.y=f2bf(v0.y); o0.z=f2bf(v0.z); o0.w=f2bf(v0.w);
    o1.x=f2bf(v1.x); o1.y=f2bf(v1.y); o1.z=f2bf(v1.z); o1.w=f2bf(v1.w);
    *(ushort4*)(whpk + c*8)     = o0;
    *(ushort4*)(whpk + c*8 + 4) = o1;
  }
  // zero flag/probe region THROUGH the coherence point (replay-safe)
  for (size_t i = tid; i < 16384; i += nth) st4coh(&bar[i], 0u);
}

// ---------------- phase B: xp = x @ W_ih^T (128x128 tile, BK=64; verified R2) ----------------
__global__ __launch_bounds__(256) void xproj_kernel(uint8_t* __restrict__ ws) {
  const ushort* __restrict__ xb = (const ushort*)(ws + OFF_XB);
  const ushort* __restrict__ wi = (const ushort*)(ws + OFF_WI);
  ushort* __restrict__ xp = (ushort*)(ws + OFF_XP);

  __shared__ ushort smA[128*64];
  __shared__ ushort smB[128*64];

  const int tid = threadIdx.x;
  const int lane = tid & 63;
  const int w = tid >> 6;
  const int bn = blockIdx.x % 24;
  const int bm = blockIdx.x / 24;
  const int m0 = bm * 128, n0 = bn * 128;
  const int mi = (w >> 1) * 64, ni = (w & 1) * 64;

  f32x4 acc[4][4] = {};

  for (int k0 = 0; k0 < D_; k0 += 64) {
    __syncthreads();
    #pragma unroll
    for (int i = 0; i < 4; ++i) {
      const int ig = w*4 + i;
      const int o  = ig*1024 + lane*16;
      const int row = o >> 7;
      const int colB = o & 127;
      const int scol = colB ^ ((row & 7) << 4);
      gload16((const uint8_t*)xb + ((size_t)(m0+row)*D_ + k0)*2 + scol,
              (uint8_t*)smA + ig*1024);
      gload16((const uint8_t*)wi + ((size_t)(n0+row)*D_ + k0)*2 + scol,
              (uint8_t*)smB + ig*1024);
    }
    __syncthreads();
    #pragma unroll
    for (int kk = 0; kk < 2; ++kk) {
      const int colB = kk*64 + (lane >> 4)*16;
      bf16x8 a[4], b[4];
      #pragma unroll
      for (int mt = 0; mt < 4; ++mt) {
        const int row = mi + mt*16 + (lane & 15);
        a[mt] = *(const bf16x8*)((const uint8_t*)smA + row*128 + (colB ^ ((row & 7) << 4)));
      }
      #pragma unroll
      for (int nt = 0; nt < 4; ++nt) {
        const int row = ni + nt*16 + (lane & 15);
        b[nt] = *(const bf16x8*)((const uint8_t*)smB + row*128 + (colB ^ ((row & 7) << 4)));
      }
      #pragma unroll
      for (int mt = 0; mt < 4; ++mt)
        #pragma unroll
        for (int nt = 0; nt < 4; ++nt)
          acc[mt][nt] = __builtin_amdgcn_mfma_f32_16x16x32_bf16(a[mt], b[nt], acc[mt][nt], 0, 0, 0);
    }
  }
  #pragma unroll
  for (int mt = 0; mt < 4; ++mt)
    #pragma unroll
    for (int nt = 0; nt < 4; ++nt) {
      const int r0 = m0 + mi + mt*16 + (lane >> 4)*4;
      const int c  = n0 + ni + nt*16 + (lane & 15);
      #pragma unroll
      for (int r = 0; r < 4; ++r)
        xp[(size_t)(r0 + r)*NG + c] = f2bf(acc[mt][nt][r]);
    }
}

// ---------------- phase C: persistent recurrence, L1-inv + L2 flags ----------------
// 256 WGs, 1/CU. 8 groups x 32 strips. Local mode: flagA sc0 post + buffer_inv/sc0
// poll (XCD-L2 latency); flagB sc1 separate line = liveness escape + fallback.
template<bool SC1>
__device__ __forceinline__ void run_loop(uint8_t* ws, const ushort* whh_lds, float* gbuf,
                                         ushort* hstage,
                                         const float* bih, const float* bhh,
                                         int tid, int g, int s) {
  const int lane = tid & 63, w = tid >> 6, wq = w & 1, wm = w >> 1;
  const int l15 = lane & 15, hi = lane >> 4;
  ushort* hb = (ushort*)(ws + OFF_H);
  const ushort* xp = (const ushort*)(ws + OFF_XP);
  float* hT = (float*)(ws + OFF_HT);
  unsigned* bar = (unsigned*)(ws + OFF_BAR);
  float* gw = gbuf + w*816;

  float bias[3][4];
  #pragma unroll
  for (int j = 0; j < 3; ++j) {
    const int col = s*24 + wq*12 + hi + 4*j;
    #pragma unroll
    for (int q = 0; q < 4; ++q) bias[j][q] = bih[q*H_ + col] + bhh[q*H_ + col];
  }
  const int pl = (lane < 32) ? lane : 31;
  const unsigned* fpA = bar + (size_t)(g*32 + pl) * 16;
  const unsigned* fpB = bar + 2048 + (size_t)(g*32 + pl) * 16;

  // per-thread xp source: row = g*32+wm*16+l15, cols q*768 + s*24+wq*12+hi (+4j)
  const ushort* xpb = xp + (size_t)(g*32 + wm*16 + l15)*NG + s*24 + wq*12 + hi;
  ushort xq[12];   // [q][j], plain loads (compiler-managed waitcnt)
  {
    const ushort* p = xpb;
    #pragma unroll
    for (int q = 0; q < 4; ++q)
      #pragma unroll
      for (int j = 0; j < 3; ++j)
        xq[q*3+j] = p[q*768 + 4*j];
  }

  float cc[3] = {0.f, 0.f, 0.f};

  #pragma unroll 1
  for (int t = 0; t < T_; ++t) {
    f32x4 acc[3] = {};
    if (t > 0) {
      if (w == 0) {   // wait: all 32 strips posted h(t)
        int spins = 0;
        while (1) {
          unsigned v;
          if (!SC1 && spins < 8) { l1_inv(); v = ld4sc0(fpA); }  // L2-latency fast path
          else                   { v = ld4coh(fpB); }           // L3 liveness path
          if (__all((int)(v >= (unsigned)t))) break;
          ++spins;
          __builtin_amdgcn_s_sleep(1);
        }
      }
      __syncthreads();
      // h A-frags: 24 x 16B loads (L2-local in intra-XCD mode)
      const ushort* hr = hb + ((size_t)(t & 1)*8 + g)*((size_t)32*H_)
                         + (size_t)(wm*16 + l15)*H_ + hi*8;
      u32x4 ah[24];
      #define LH(i) ah[i] = ld16<(i)*64, SC1>(hr)
      LH(0); LH(1); LH(2); LH(3); LH(4); LH(5); LH(6); LH(7);
      LH(8); LH(9); LH(10); LH(11); LH(12); LH(13); LH(14); LH(15);
      LH(16); LH(17); LH(18); LH(19); LH(20); LH(21); LH(22); LH(23);
      #undef LH
      asm volatile("s_waitcnt vmcnt(0)" ::: "memory");
      __builtin_amdgcn_sched_barrier(0);
      #pragma unroll
      for (int kf = 0; kf < 24; ++kf) {
        const bf16x8 a = *(const bf16x8*)&ah[kf];
        #pragma unroll
        for (int n = 0; n < 3; ++n) {
          const bf16x8 b = *(const bf16x8*)(whh_lds + (size_t)((kf*6 + wq*3 + n)*64 + lane)*8);
          acc[n] = __builtin_amdgcn_mfma_f32_16x16x32_bf16(a, b, acc[n], 0, 0, 0);
        }
      }
    }
    // gate xpose (wave-local LDS region, no barrier) + activations (+ xp + bias)
    #pragma unroll
    for (int n = 0; n < 3; ++n)
      #pragma unroll
      for (int r = 0; r < 4; ++r)
        gw[(n*16 + l15)*17 + hi*4 + r] = acc[n][r];
    float hv[3];
    #pragma unroll
    for (int j = 0; j < 3; ++j) {
      const int cl = hi + 4*j;
      float gq[4];
      #pragma unroll
      for (int q = 0; q < 4; ++q) {
        union { unsigned u; float f; } xv; xv.u = ((unsigned)xq[q*3 + j]) << 16;
        gq[q] = gw[(cl*4+q)*17 + l15] + xv.f + bias[j][q];
      }
      const float iv = sigf(gq[0]);
      const float fv = sigf(gq[1]);
      const float gv = tanhf_(gq[2]);
      const float ov = sigf(gq[3]);
      const float cn = fv*cc[j] + iv*gv;
      cc[j] = cn;
      hv[j] = ov * tanhf_(cn);
    }
    const int rowl = wm*16 + l15;
    if (t == T_-1) {
      #pragma unroll
      for (int j = 0; j < 3; ++j) {
        const int col = s*24 + wq*12 + hi + 4*j;
        hT[(size_t)(g*32 + rowl)*H_ + col] = hv[j];
      }
      break;
    }
    // stage h in LDS, then 96 coalesced 16B stores (R8/R13-validated mapping)
    #pragma unroll
    for (int j = 0; j < 3; ++j)
      hstage[rowl*24 + wq*12 + hi + 4*j] = f2bf(hv[j]);
    __syncthreads();
    ushort* hn = hb + ((size_t)((t+1) & 1)*8 + g)*((size_t)32*H_);
    if (tid < 96) {
      const int row = tid / 3, part = tid % 3;
      const u32x4 v = *(const u32x4*)((const uint8_t*)hstage + row*48 + part*16);
      st16g<SC1>(hn + (size_t)row*H_ + s*24 + part*8, v);
    }
    asm volatile("s_waitcnt vmcnt(0)" ::: "memory");   // stores landed (L2 / coh pt)
    __syncthreads();                                    // all 96 stores acked
    if (tid == 0) {
      if (!SC1) st4sc0((unsigned*)fpA - pl*16 + s*16, 0);  // placeholder no-op guard
    }
    if (tid == 0) {
      unsigned* fA = bar + (size_t)(g*32 + s)*16;          // sc0-only line
      unsigned* fB = bar + 2048 + (size_t)(g*32 + s)*16;   // sc1-only line
      if (!SC1) st4sc0(fA, (unsigned)(t + 1));
      st4coh(fB, (unsigned)(t + 1));
    }
    {  // prefetch xp(t+1) in the post-flag slack (plain loads)
      const ushort* p = xpb + (size_t)(t + 1)*B_*NG;
      #pragma unroll
      for (int q = 0; q < 4; ++q)
        #pragma unroll
        for (int j = 0; j < 3; ++j)
          xq[q*3+j] = p[q*768 + 4*j];
    }
  }
}

__global__ __launch_bounds__(256, 1) void lstm_kernel(uint8_t* __restrict__ ws,
                                                      const float* __restrict__ bih,
                                                      const float* __restrict__ bhh) {
  __shared__ ushort whh_lds[73728];   // 144 KB: [kf 24][nt 6][64] 16B frag chunks
  __shared__ float gbuf[3264];        // 12.75 KB
  __shared__ ushort hstage[768];      // 1.5 KB: [row 32][col 24]
  const int tid = threadIdx.x, lane = tid & 63, w = tid >> 6;
  const int g = blockIdx.x & 7, s = blockIdx.x >> 3;
  unsigned* bar = (unsigned*)(ws + OFF_BAR);

  const uint8_t* wsrc = ws + OFF_WHPK + (size_t)s*9216*16;
  #pragma unroll
  for (int i = 0; i < 36; ++i) {
    const int cb = (w*36 + i)*64;
    gload16(wsrc + (size_t)(cb + lane)*16, (uint8_t*)whh_lds + (size_t)cb*16);
  }

  // publish XCC_ID (sc1); one-time global init barrier (system atomic)
  const unsigned xcd = __builtin_amdgcn_s_getreg((3 << 11) | 20) & 7u;  // HW_REG_XCC_ID
  if (tid == 0) {
    st4coh(bar + 4096 + blockIdx.x, xcd);
    asm volatile("s_waitcnt vmcnt(0)" ::: "memory");
    __hip_atomic_fetch_add(bar + 5120, 1u, __ATOMIC_RELAXED, __HIP_MEMORY_SCOPE_SYSTEM);
    while (__hip_atomic_load(bar + 5120, __ATOMIC_RELAXED, __HIP_MEMORY_SCOPE_SYSTEM) < 256u)
      __builtin_amdgcn_s_sleep(2);
  }
  __syncthreads();
  const int pl = (lane < 32) ? lane : 31;
  const unsigned oxcc = ld4coh(bar + 4096 + g + 8*pl);   // peers of my group
  const bool local = __all((int)(oxcc == xcd));

  asm volatile("s_waitcnt vmcnt(0) lgkmcnt(0)" ::: "memory");
  __syncthreads();                                 // whh_lds fully staged

  if (local) run_loop<false>(ws, whh_lds, gbuf, hstage, bih, bhh, tid, g, s);
  else       run_loop<true >(ws, whh_lds, gbuf, hstage, bih, bhh, tid, g, s);
}

// ---------------- phase D: out = h_T @ W_fc^T + b_fc ----------------
__global__ __launch_bounds__(64) void fc_kernel(const uint8_t* __restrict__ ws,
                                                const float* __restrict__ wfc,
                                                const float* __restrict__ bfc,
                                                float* __restrict__ out) {
  const float* hT = (const float*)(ws + OFF_HT);
  const int b = blockIdx.x;
  const int lane = threadIdx.x;
  const float* hr = hT + (size_t)b*H_;
  float hv[12];
  #pragma unroll
  for (int i = 0; i < 12; ++i) hv[i] = hr[lane + i*64];
  for (int o = 0; o < OUT_; ++o) {
    const float* wr = wfc + (size_t)o*H_;
    float sum = 0.f;
    #pragma unroll
    for (int i = 0; i < 12; ++i) sum += hv[i] * wr[lane + i*64];
    #pragma unroll
    for (int off = 32; off; off >>= 1) sum += __shfl_xor(sum, off);
    if (lane == 0) out[(size_t)b*OUT_ + o] = sum + bfc[o];
  }
}

extern "C" void kernel_launch(void* const* d_in, const int* in_sizes, int n_in,
                              void* d_out, int out_size, void* d_ws, size_t ws_size,
                              hipStream_t stream) {
  const float* x   = (const float*)d_in[0];
  const float* wih = (const float*)d_in[1];
  const float* whh = (const float*)d_in[2];
  const float* bih = (const float*)d_in[3];
  const float* bhh = (const float*)d_in[4];
  const float* wfc = (const float*)d_in[5];
  const float* bfc = (const float*)d_in[6];
  uint8_t* ws = (uint8_t*)d_ws;
  float* out = (float*)d_out;

  prep_kernel<<<dim3(2048), dim3(256), 0, stream>>>(x, wih, whh, ws);
  xproj_kernel<<<dim3(256*24), dim3(256), 0, stream>>>(ws);
  lstm_kernel<<<dim3(256), dim3(256), 0, stream>>>(ws, bih, bhh);
  fc_kernel<<<dim3(256), dim3(64), 0, stream>>>(ws, wfc, bfc, out);
}

// Round 15
// 985.922 us; speedup vs baseline: 2.5159x; 1.0451x over previous
//
#include <hip/hip_runtime.h>
#include <stdint.h>

#define T_ 128
#define B_ 256
#define D_ 512
#define H_ 768
#define NG 3072   // 4*H
#define OUT_ 60

using bf16x8 = __attribute__((ext_vector_type(8))) __bf16;
using f32x4  = __attribute__((ext_vector_type(4))) float;
using u32x4  = __attribute__((ext_vector_type(4))) unsigned int;

// ---------------- ws layout (bytes) ----------------
#define OFF_XB   ((size_t)0)                        // x bf16 linear [T*B][D]
#define OFF_WI   (OFF_XB + (size_t)T_*B_*D_*2)      // W_ih bf16 linear [NG][D]
#define OFF_WHPK (OFF_WI + (size_t)NG*D_*2)         // W_hh frag-packed per strip
#define OFF_H    (OFF_WHPK + (size_t)NG*H_*2)       // h dbuf [2][8g][32][768] bf16
#define OFF_HT   (OFF_H + (size_t)2*B_*H_*2)        // final h f32
#define OFF_BAR  (OFF_HT + (size_t)B_*H_*4)         // flags/probe, 64KB
#define OFF_XP   (OFF_BAR + 65536)                  // xp row-major [T*B][NG] bf16, 201MB
#define OFF_END  (OFF_XP + (size_t)T_*B_*NG*2)
// bar[] u32 map: flags [(g*32+s)*16] — sc1 ONLY (R7-proven semantics);
// xcc publish [4096+blk]; init ctr [5120]

__device__ __forceinline__ unsigned short f2bf(float f) {
  union { float f; unsigned u; } v; v.f = f;
  unsigned r = (v.u + 0x7fffu + ((v.u >> 16) & 1u)) >> 16;  // RNE
  return (unsigned short)r;
}
__device__ __forceinline__ float sigf(float x) {
  return __builtin_amdgcn_rcpf(1.0f + __expf(-x));
}
__device__ __forceinline__ float tanhf_(float x) {
  return 2.0f * __builtin_amdgcn_rcpf(1.0f + __expf(-2.0f * x)) - 1.0f;
}
__device__ __forceinline__ void gload16(const void* g, void* l) {
  __builtin_amdgcn_global_load_lds(
      (const __attribute__((address_space(1))) unsigned int*)g,
      (__attribute__((address_space(3))) unsigned int*)l, 16, 0, 0);
}
template<int OFF, bool SC1>
__device__ __forceinline__ u32x4 ld16(const void* p) {
  u32x4 r;
  if constexpr (SC1)
    asm volatile("global_load_dwordx4 %0, %1, off offset:%c2 sc0 sc1"
                 : "=v"(r) : "v"(p), "i"(OFF) : "memory");
  else
    asm volatile("global_load_dwordx4 %0, %1, off offset:%c2 sc0"
                 : "=v"(r) : "v"(p), "i"(OFF) : "memory");
  return r;
}
__device__ __forceinline__ unsigned ld4coh(const unsigned* p) {  // sc1 poll (+wait)
  unsigned r;
  asm volatile("global_load_dword %0, %1, off sc0 sc1\n\ts_waitcnt vmcnt(0)"
               : "=v"(r) : "v"(p) : "memory");
  return r;
}
template<bool SC1>
__device__ __forceinline__ void st2(ushort* p, unsigned v) {
  if constexpr (SC1)
    asm volatile("global_store_short %0, %1, off sc0 sc1" :: "v"(p), "v"(v) : "memory");
  else
    asm volatile("global_store_short %0, %1, off sc0" :: "v"(p), "v"(v) : "memory");
}
__device__ __forceinline__ void st4coh(unsigned* p, unsigned v) {
  asm volatile("global_store_dword %0, %1, off sc0 sc1" :: "v"(p), "v"(v) : "memory");
}

// ---------------- phase A: convert + pack + init ----------------
__global__ void prep_kernel(const float* __restrict__ x,
                            const float* __restrict__ wihf,
                            const float* __restrict__ whhf,
                            uint8_t* __restrict__ ws) {
  ushort* xb = (ushort*)(ws + OFF_XB);
  ushort* wi = (ushort*)(ws + OFF_WI);
  ushort* whpk = (ushort*)(ws + OFF_WHPK);
  unsigned* bar = (unsigned*)(ws + OFF_BAR);
  const size_t tid = (size_t)blockIdx.x * blockDim.x + threadIdx.x;
  const size_t nth = (size_t)gridDim.x * blockDim.x;

  for (size_t i = tid; i < (size_t)T_*B_*D_/4; i += nth) {
    float4 v = ((const float4*)x)[i];
    ushort4 o; o.x=f2bf(v.x); o.y=f2bf(v.y); o.z=f2bf(v.z); o.w=f2bf(v.w);
    ((ushort4*)xb)[i] = o;
  }
  for (size_t i = tid; i < (size_t)NG*D_/4; i += nth) {
    float4 v = ((const float4*)wihf)[i];
    ushort4 o; o.x=f2bf(v.x); o.y=f2bf(v.y); o.z=f2bf(v.z); o.w=f2bf(v.w);
    ((ushort4*)wi)[i] = o;
  }
  // W_hh -> frag-packed per strip: chunk ((s*24+kf)*6+nt)*64+L  (verified R5)
  for (size_t c = tid; c < (size_t)294912; c += nth) {
    const unsigned L = (unsigned)c & 63u;
    const unsigned r1 = (unsigned)(c >> 6);
    const unsigned nt = r1 % 6u, r2 = r1 / 6u;
    const unsigned kf = r2 % 24u, s = r2 / 24u;
    const unsigned i = nt*16u + (L & 15u);
    const unsigned G = (i & 3u)*768u + s*24u + (i >> 2);
    const unsigned k0 = kf*32u + (L >> 4)*8u;
    const float4 v0 = *(const float4*)(whhf + (size_t)G*768u + k0);
    const float4 v1 = *(const float4*)(whhf + (size_t)G*768u + k0 + 4);
    ushort4 o0, o1;
    o0.x=f2bf(v0.x); o0.y=f2bf(v0.y); o0.z=f2bf(v0.z); o0.w=f2bf(v0.w);
    o1.x=f2bf(v1.x); o1.y=f2bf(v1.y); o1.z=f2bf(v1.z); o1.w=f2bf(v1.w);
    *(ushort4*)(whpk + c*8)     = o0;
    *(ushort4*)(whpk + c*8 + 4) = o1;
  }
  // zero flag/probe region THROUGH the coherence point (replay-safe)
  for (size_t i = tid; i < 16384; i += nth) st4coh(&bar[i], 0u);
}

// ---------------- phase B: xp = x @ W_ih^T (128x128 tile, BK=64; verified R2) ----------------
__global__ __launch_bounds__(256) void xproj_kernel(uint8_t* __restrict__ ws) {
  const ushort* __restrict__ xb = (const ushort*)(ws + OFF_XB);
  const ushort* __restrict__ wi = (const ushort*)(ws + OFF_WI);
  ushort* __restrict__ xp = (ushort*)(ws + OFF_XP);

  __shared__ ushort smA[128*64];
  __shared__ ushort smB[128*64];

  const int tid = threadIdx.x;
  const int lane = tid & 63;
  const int w = tid >> 6;
  const int bn = blockIdx.x % 24;
  const int bm = blockIdx.x / 24;
  const int m0 = bm * 128, n0 = bn * 128;
  const int mi = (w >> 1) * 64, ni = (w & 1) * 64;

  f32x4 acc[4][4] = {};

  for (int k0 = 0; k0 < D_; k0 += 64) {
    __syncthreads();
    #pragma unroll
    for (int i = 0; i < 4; ++i) {
      const int ig = w*4 + i;
      const int o  = ig*1024 + lane*16;
      const int row = o >> 7;
      const int colB = o & 127;
      const int scol = colB ^ ((row & 7) << 4);
      gload16((const uint8_t*)xb + ((size_t)(m0+row)*D_ + k0)*2 + scol,
              (uint8_t*)smA + ig*1024);
      gload16((const uint8_t*)wi + ((size_t)(n0+row)*D_ + k0)*2 + scol,
              (uint8_t*)smB + ig*1024);
    }
    __syncthreads();
    #pragma unroll
    for (int kk = 0; kk < 2; ++kk) {
      const int colB = kk*64 + (lane >> 4)*16;
      bf16x8 a[4], b[4];
      #pragma unroll
      for (int mt = 0; mt < 4; ++mt) {
        const int row = mi + mt*16 + (lane & 15);
        a[mt] = *(const bf16x8*)((const uint8_t*)smA + row*128 + (colB ^ ((row & 7) << 4)));
      }
      #pragma unroll
      for (int nt = 0; nt < 4; ++nt) {
        const int row = ni + nt*16 + (lane & 15);
        b[nt] = *(const bf16x8*)((const uint8_t*)smB + row*128 + (colB ^ ((row & 7) << 4)));
      }
      #pragma unroll
      for (int mt = 0; mt < 4; ++mt)
        #pragma unroll
        for (int nt = 0; nt < 4; ++nt)
          acc[mt][nt] = __builtin_amdgcn_mfma_f32_16x16x32_bf16(a[mt], b[nt], acc[mt][nt], 0, 0, 0);
    }
  }
  #pragma unroll
  for (int mt = 0; mt < 4; ++mt)
    #pragma unroll
    for (int nt = 0; nt < 4; ++nt) {
      const int r0 = m0 + mi + mt*16 + (lane >> 4)*4;
      const int c  = n0 + ni + nt*16 + (lane & 15);
      #pragma unroll
      for (int r = 0; r < 4; ++r)
        xp[(size_t)(r0 + r)*NG + c] = f2bf(acc[mt][nt][r]);
    }
}

// ---------------- phase C: persistent recurrence (R7 structure, all-waves poll) ----------------
// 256 WGs, 1/CU. 8 groups x 32 strips. Flags: sc1 post + sc1 poll (proven).
// Change vs R7: ALL 4 waves poll independently -> no barriers on the release path.
template<bool SC1>
__device__ __forceinline__ void run_loop(uint8_t* ws, const ushort* whh_lds, float* gbuf,
                                         const float* bih, const float* bhh,
                                         int tid, int g, int s) {
  const int lane = tid & 63, w = tid >> 6, wq = w & 1, wm = w >> 1;
  const int l15 = lane & 15, hi = lane >> 4;
  ushort* hb = (ushort*)(ws + OFF_H);
  const ushort* xp = (const ushort*)(ws + OFF_XP);
  float* hT = (float*)(ws + OFF_HT);
  unsigned* bar = (unsigned*)(ws + OFF_BAR);
  float* gw = gbuf + w*816;

  float bias[3][4];
  #pragma unroll
  for (int j = 0; j < 3; ++j) {
    const int col = s*24 + wq*12 + hi + 4*j;
    #pragma unroll
    for (int q = 0; q < 4; ++q) bias[j][q] = bih[q*H_ + col] + bhh[q*H_ + col];
  }
  const int pl = (lane < 32) ? lane : 31;
  const unsigned* fp = bar + (size_t)(g*32 + pl) * 16;

  // per-thread xp source: row = g*32+wm*16+l15, cols q*768 + s*24+wq*12+hi (+4j)
  const ushort* xpb = xp + (size_t)(g*32 + wm*16 + l15)*NG + s*24 + wq*12 + hi;
  ushort xq[12];   // [q][j], plain loads (compiler-managed waitcnt)
  {
    const ushort* p = xpb;
    #pragma unroll
    for (int q = 0; q < 4; ++q)
      #pragma unroll
      for (int j = 0; j < 3; ++j)
        xq[q*3+j] = p[q*768 + 4*j];
  }

  float cc[3] = {0.f, 0.f, 0.f};

  #pragma unroll 1
  for (int t = 0; t < T_; ++t) {
    f32x4 acc[3] = {};
    if (t > 0) {
      // ALL waves poll independently: each wave proceeds the moment it sees
      // all 32 strips posted h(t). No __syncthreads on the release path.
      while (1) {
        const unsigned v = ld4coh(fp);
        if (__all((int)(v >= (unsigned)t))) break;
        __builtin_amdgcn_s_sleep(1);
      }
      // h A-frags: 24 x 16B loads (L2-local in intra-XCD mode)
      const ushort* hr = hb + ((size_t)(t & 1)*8 + g)*((size_t)32*H_)
                         + (size_t)(wm*16 + l15)*H_ + hi*8;
      u32x4 ah[24];
      #define LH(i) ah[i] = ld16<(i)*64, SC1>(hr)
      LH(0); LH(1); LH(2); LH(3); LH(4); LH(5); LH(6); LH(7);
      LH(8); LH(9); LH(10); LH(11); LH(12); LH(13); LH(14); LH(15);
      LH(16); LH(17); LH(18); LH(19); LH(20); LH(21); LH(22); LH(23);
      #undef LH
      asm volatile("s_waitcnt vmcnt(0)" ::: "memory");
      __builtin_amdgcn_sched_barrier(0);
      #pragma unroll
      for (int kf = 0; kf < 24; ++kf) {
        const bf16x8 a = *(const bf16x8*)&ah[kf];
        #pragma unroll
        for (int n = 0; n < 3; ++n) {
          const bf16x8 b = *(const bf16x8*)(whh_lds + (size_t)((kf*6 + wq*3 + n)*64 + lane)*8);
          acc[n] = __builtin_amdgcn_mfma_f32_16x16x32_bf16(a, b, acc[n], 0, 0, 0);
        }
      }
    }
    // gate xpose (wave-local LDS region, no barrier) + activations (+ xp + bias)
    #pragma unroll
    for (int n = 0; n < 3; ++n)
      #pragma unroll
      for (int r = 0; r < 4; ++r)
        gw[(n*16 + l15)*17 + hi*4 + r] = acc[n][r];
    float hv[3];
    #pragma unroll
    for (int j = 0; j < 3; ++j) {
      const int cl = hi + 4*j;
      float gq[4];
      #pragma unroll
      for (int q = 0; q < 4; ++q) {
        union { unsigned u; float f; } xv; xv.u = ((unsigned)xq[q*3 + j]) << 16;
        gq[q] = gw[(cl*4+q)*17 + l15] + xv.f + bias[j][q];
      }
      const float iv = sigf(gq[0]);
      const float fv = sigf(gq[1]);
      const float gv = tanhf_(gq[2]);
      const float ov = sigf(gq[3]);
      const float cn = fv*cc[j] + iv*gv;
      cc[j] = cn;
      hv[j] = ov * tanhf_(cn);
    }
    const int rowl = wm*16 + l15;
    if (t == T_-1) {
      #pragma unroll
      for (int j = 0; j < 3; ++j) {
        const int col = s*24 + wq*12 + hi + 4*j;
        hT[(size_t)(g*32 + rowl)*H_ + col] = hv[j];
      }
      break;
    }
    // direct 2B h-stores (R7-proven: faster than LDS-stage + 16B, cf. R14)
    ushort* hn = hb + ((size_t)((t+1) & 1)*8 + g)*((size_t)32*H_);
    #pragma unroll
    for (int j = 0; j < 3; ++j) {
      const int col = s*24 + wq*12 + hi + 4*j;
      st2<SC1>(hn + (size_t)rowl*H_ + col, (unsigned)f2bf(hv[j]));
    }
    asm volatile("s_waitcnt vmcnt(0)" ::: "memory");   // own h stores done
    __syncthreads();                                    // all waves' stores done
    if (tid == 0) st4coh(bar + (size_t)(g*32 + s)*16, (unsigned)(t + 1));
    {  // prefetch xp(t+1) in the post-flag slack (plain loads)
      const ushort* p = xpb + (size_t)(t + 1)*B_*NG;
      #pragma unroll
      for (int q = 0; q < 4; ++q)
        #pragma unroll
        for (int j = 0; j < 3; ++j)
          xq[q*3+j] = p[q*768 + 4*j];
    }
  }
}

__global__ __launch_bounds__(256, 1) void lstm_kernel(uint8_t* __restrict__ ws,
                                                      const float* __restrict__ bih,
                                                      const float* __restrict__ bhh) {
  __shared__ ushort whh_lds[73728];   // 144 KB: [kf 24][nt 6][64] 16B frag chunks
  __shared__ float gbuf[3264];        // 12.75 KB
  const int tid = threadIdx.x, lane = tid & 63, w = tid >> 6;
  const int g = blockIdx.x & 7, s = blockIdx.x >> 3;
  unsigned* bar = (unsigned*)(ws + OFF_BAR);

  const uint8_t* wsrc = ws + OFF_WHPK + (size_t)s*9216*16;
  #pragma unroll
  for (int i = 0; i < 36; ++i) {
    const int cb = (w*36 + i)*64;
    gload16(wsrc + (size_t)(cb + lane)*16, (uint8_t*)whh_lds + (size_t)cb*16);
  }

  // publish XCC_ID (sc1); one-time global init barrier (system atomic)
  const unsigned xcd = __builtin_amdgcn_s_getreg((3 << 11) | 20) & 7u;  // HW_REG_XCC_ID
  if (tid == 0) {
    st4coh(bar + 4096 + blockIdx.x, xcd);
    asm volatile("s_waitcnt vmcnt(0)" ::: "memory");
    __hip_atomic_fetch_add(bar + 5120, 1u, __ATOMIC_RELAXED, __HIP_MEMORY_SCOPE_SYSTEM);
    while (__hip_atomic_load(bar + 5120, __ATOMIC_RELAXED, __HIP_MEMORY_SCOPE_SYSTEM) < 256u)
      __builtin_amdgcn_s_sleep(2);
  }
  __syncthreads();
  const int pl = (lane < 32) ? lane : 31;
  const unsigned oxcc = ld4coh(bar + 4096 + g + 8*pl);   // peers of my group
  const bool local = __all((int)(oxcc == xcd));

  asm volatile("s_waitcnt vmcnt(0) lgkmcnt(0)" ::: "memory");
  __syncthreads();                                 // whh_lds fully staged

  if (local) run_loop<false>(ws, whh_lds, gbuf, bih, bhh, tid, g, s);
  else       run_loop<true >(ws, whh_lds, gbuf, bih, bhh, tid, g, s);
}

// ---------------- phase D: out = h_T @ W_fc^T + b_fc ----------------
__global__ __launch_bounds__(64) void fc_kernel(const uint8_t* __restrict__ ws,
                                                const float* __restrict__ wfc,
                                                const float* __restrict__ bfc,
                                                float* __restrict__ out) {
  const float* hT = (const float*)(ws + OFF_HT);
  const int b = blockIdx.x;
  const int lane = threadIdx.x;
  const float* hr = hT + (size_t)b*H_;
  float hv[12];
  #pragma unroll
  for (int i = 0; i < 12; ++i) hv[i] = hr[lane + i*64];
  for (int o = 0; o < OUT_; ++o) {
    const float* wr = wfc + (size_t)o*H_;
    float sum = 0.f;
    #pragma unroll
    for (int i = 0; i < 12; ++i) sum += hv[i] * wr[lane + i*64];
    #pragma unroll
    for (int off = 32; off; off >>= 1) sum += __shfl_xor(sum, off);
    if (lane == 0) out[(size_t)b*OUT_ + o] = sum + bfc[o];
  }
}

extern "C" void kernel_launch(void* const* d_in, const int* in_sizes, int n_in,
                              void* d_out, int out_size, void* d_ws, size_t ws_size,
                              hipStream_t stream) {
  const float* x   = (const float*)d_in[0];
  const float* wih = (const float*)d_in[1];
  const float* whh = (const float*)d_in[2];
  const float* bih = (const float*)d_in[3];
  const float* bhh = (const float*)d_in[4];
  const float* wfc = (const float*)d_in[5];
  const float* bfc = (const float*)d_in[6];
  uint8_t* ws = (uint8_t*)d_ws;
  float* out = (float*)d_out;

  prep_kernel<<<dim3(2048), dim3(256), 0, stream>>>(x, wih, whh, ws);
  xproj_kernel<<<dim3(256*24), dim3(256), 0, stream>>>(ws);
  lstm_kernel<<<dim3(256), dim3(256), 0, stream>>>(ws, bih, bhh);
  fc_kernel<<<dim3(256), dim3(64), 0, stream>>>(ws, wfc, bfc, out);
}